// Round 3
// baseline (2129.023 us; speedup 1.0000x reference)
//
#include <hip/hip_runtime.h>
#include <math.h>

#define B_ 32
#define INLEN 10
#define LIN_ 16384
#define NPOLY 12
#define MM 6
#define CH 20
#define NB 4
#define RECEPT 25
#define L0 16434      // length after first conv
#define TTILE 144     // outputs per tile (multiple of 6)
#define NW 25         // windows needed: wl in [0, 24]
#define XS_LEN 156    // TTILE + 12 halo
#define XS_PAD 157    // odd stride -> conflict-free strided column reads
#define GS_LEN 146    // TTILE + 2
#define GS_PAD 147

__device__ __forceinline__ float gelu_exact(float x) {
    return 0.5f * x * (1.0f + erff(x * 0.70710678118654752440f));
}

// ---------------- first conv: (B,10,16384) wrap-padded -> (B,20,16434) ----------------
__global__ void k_first(const float* __restrict__ in, const float* __restrict__ wf,
                        float* __restrict__ out) {
    int t = blockIdx.x * blockDim.x + threadIdx.x;
    int b = blockIdx.y;
    if (t >= L0) return;
    const float* inb = in + (size_t)b * INLEN * LIN_;
    float xw[INLEN][3];
#pragma unroll
    for (int ci = 0; ci < INLEN; ++ci) {
#pragma unroll
        for (int k = 0; k < 3; ++k) {
            int idx = t + k - RECEPT;
            idx = (idx < 0) ? idx + LIN_ : (idx >= LIN_ ? idx - LIN_ : idx);
            xw[ci][k] = inb[ci * LIN_ + idx];
        }
    }
    float* outb = out + (size_t)b * CH * L0;
#pragma unroll
    for (int co = 0; co < CH; ++co) {
        float acc = 0.f;
#pragma unroll
        for (int ci = 0; ci < INLEN; ++ci)
#pragma unroll
            for (int k = 0; k < 3; ++k)
                acc = fmaf(xw[ci][k], wf[(co * INLEN + ci) * 3 + k], acc);
        outb[(size_t)co * L0 + t] = acc;
    }
}

// ---------------- fused block: residual conv path + Legendre multiwavelet path ----------------
__global__ __launch_bounds__(256, 2)
void k_block(const float* __restrict__ x, float* __restrict__ xn,
             const float* __restrict__ wA, const float* __restrict__ wB,
             const float* __restrict__ linm, const float* __restrict__ fd,
             const float* __restrict__ fr, int l) {
    const int lout = l - 12;
    const int tid  = threadIdx.x;
    const int t0   = blockIdx.x * TTILE;       // multiple of 6
    const int b    = blockIdx.y;

    __shared__ float xs[CH][XS_PAD];                           // 12560 B
    __shared__ float gs[CH][GS_PAD];                           // 11760 B
    __shared__ __attribute__((aligned(16))) float lxs[NW * 120]; // 12000 B : [wl][u], u=m*20+c
    __shared__ float fr_s[MM * NPOLY];                         // 288 B
    // total ~36.6 KB -> 4 blocks/CU

    const float* xb = x + (size_t)b * CH * l;

    if (tid < MM * NPOLY) fr_s[tid] = fr[tid];

    // stage A: load x tile (zero-fill past end; those outputs are masked)
    for (int i = tid; i < CH * XS_LEN; i += 256) {
        int c = i / XS_LEN, p = i - c * XS_LEN;
        int gp = t0 + p;
        xs[c][p] = (gp < l) ? xb[(size_t)c * l + gp] : 0.f;
    }
    __syncthreads();

    // stage B: gs[co][j] = gelu(conv_a(x)) at position t0+4+j, j in [0, GS_LEN)
    if (tid < GS_LEN) {
        float acc[CH];
#pragma unroll
        for (int co = 0; co < CH; ++co) acc[co] = 0.f;
#pragma unroll
        for (int ci = 0; ci < CH; ++ci) {
            float x0 = xs[ci][tid + 4];
            float x1 = xs[ci][tid + 5];
            float x2 = xs[ci][tid + 6];
#pragma unroll
            for (int co = 0; co < CH; ++co) {
                const float* w = wA + (co * CH + ci) * 3;
                acc[co] = fmaf(x0, w[0], acc[co]);
                acc[co] = fmaf(x1, w[1], acc[co]);
                acc[co] = fmaf(x2, w[2], acc[co]);
            }
        }
#pragma unroll
        for (int co = 0; co < CH; ++co) gs[co][tid] = gelu_exact(acc[co]);
    }

    // stage C1: Legendre decomposition per (window, channel); fd reads are wave-uniform -> s_load
    for (int item = tid; item < NW * CH; item += 256) {
        int wl = item / CH, c = item - wl * CH;
        float xv[NPOLY];
#pragma unroll
        for (int k = 0; k < NPOLY; ++k) xv[k] = xs[c][6 * wl + k];
#pragma unroll
        for (int m = 0; m < MM; ++m) {
            float a = 0.f;
#pragma unroll
            for (int k = 0; k < NPOLY; ++k)
                a = fmaf(xv[k], fd[m * NPOLY + k], a);
            lxs[wl * 120 + m * CH + c] = a * 0.5f;
        }
    }
    __syncthreads();

    // stage C2: grouped 6x6 mode mixing in place (u = m*20+c flattened; groups = 6-consecutive u)
    for (int item = tid; item < NW * CH; item += 256) {
        int wl = item / CH, gg = item - wl * CH;
        float iv[MM], ov[MM];
#pragma unroll
        for (int i = 0; i < MM; ++i) iv[i] = lxs[wl * 120 + gg * MM + i];
        const float* lw = linm + gg * (MM * MM);
#pragma unroll
        for (int o = 0; o < MM; ++o) {
            float a = 0.f;
#pragma unroll
            for (int i = 0; i < MM; ++i)
                a = fmaf(iv[i], lw[o * MM + i], a);
            ov[o] = a;
        }
#pragma unroll
        for (int o = 0; o < MM; ++o) lxs[wl * 120 + gg * MM + o] = ov[o];
    }
    __syncthreads();

    // stage D: out[t0+tp] = gelu( rec + conv_b(g) )
    if (tid < TTILE && t0 + tid < lout) {
        const int tp = tid;
        float acc[CH];
#pragma unroll
        for (int co = 0; co < CH; ++co) acc[co] = 0.f;
        // conv_b, ci-outer from LDS (stride-1 reads, free 2-way aliasing)
#pragma unroll
        for (int ci = 0; ci < CH; ++ci) {
            float g0 = gs[ci][tp];
            float g1 = gs[ci][tp + 1];
            float g2 = gs[ci][tp + 2];
#pragma unroll
            for (int co = 0; co < CH; ++co) {
                const float* w = wB + (co * CH + ci) * 3;
                acc[co] = fmaf(g0, w[0], acc[co]);
                acc[co] = fmaf(g1, w[1], acc[co]);
                acc[co] = fmaf(g2, w[2], acc[co]);
            }
        }
        // reconstruction: m-major, 20 contiguous channels per (window, m) row -> float4 reads
        const int r1  = tp % 6;
        const int wl1 = tp / 6 + 1;
#pragma unroll
        for (int m = 0; m < MM; ++m) {
            float fa = fr_s[m * NPOLY + r1];
            float fb = fr_s[m * NPOLY + r1 + 6];
            const float4* rowA = (const float4*)&lxs[wl1 * 120 + m * CH];
            const float4* rowB = (const float4*)&lxs[(wl1 - 1) * 120 + m * CH];
#pragma unroll
            for (int q = 0; q < 5; ++q) {
                float4 va = rowA[q];
                float4 vb = rowB[q];
                acc[4 * q + 0] = fmaf(va.x, fa, acc[4 * q + 0]);
                acc[4 * q + 1] = fmaf(va.y, fa, acc[4 * q + 1]);
                acc[4 * q + 2] = fmaf(va.z, fa, acc[4 * q + 2]);
                acc[4 * q + 3] = fmaf(va.w, fa, acc[4 * q + 3]);
                acc[4 * q + 0] = fmaf(vb.x, fb, acc[4 * q + 0]);
                acc[4 * q + 1] = fmaf(vb.y, fb, acc[4 * q + 1]);
                acc[4 * q + 2] = fmaf(vb.z, fb, acc[4 * q + 2]);
                acc[4 * q + 3] = fmaf(vb.w, fb, acc[4 * q + 3]);
            }
        }
        float* xnb = xn + (size_t)b * CH * lout;
#pragma unroll
        for (int co = 0; co < CH; ++co)
            xnb[(size_t)co * lout + t0 + tp] = gelu_exact(acc[co]);
    }
}

// ---------------- final: gelu(20->128) -> 128->1, slice to 16384 ----------------
__global__ void k_final(const float* __restrict__ x, const float* __restrict__ w11,
                        const float* __restrict__ wout, float* __restrict__ out) {
    int t = blockIdx.x * blockDim.x + threadIdx.x;
    int b = blockIdx.y;
    if (t >= LIN_) return;
    const int l4 = L0 - NB * 12;   // 16386
    const float* xb = x + (size_t)b * CH * l4;
    float xv[CH];
#pragma unroll
    for (int c = 0; c < CH; ++c) xv[c] = xb[(size_t)c * l4 + t];
    float acc = 0.f;
    for (int h = 0; h < 128; ++h) {
        float hv = 0.f;
#pragma unroll
        for (int c = 0; c < CH; ++c)
            hv = fmaf(xv[c], w11[h * CH + c], hv);
        acc = fmaf(gelu_exact(hv), wout[h], acc);
    }
    out[(size_t)b * LIN_ + t] = acc;
}

extern "C" void kernel_launch(void* const* d_in, const int* in_sizes, int n_in,
                              void* d_out, int out_size, void* d_ws, size_t ws_size,
                              hipStream_t stream) {
    const float* input   = (const float*)d_in[0];
    const float* w_first = (const float*)d_in[1];
    const float* conv_a  = (const float*)d_in[2];
    const float* conv_b  = (const float*)d_in[3];
    const float* lin_m   = (const float*)d_in[4];
    const float* w11     = (const float*)d_in[5];
    const float* w_out   = (const float*)d_in[6];
    const float* filt_d  = (const float*)d_in[7];
    const float* filt_r  = (const float*)d_in[8];
    float* out = (float*)d_out;

    const size_t bufElems = (size_t)B_ * CH * L0;   // 10,517,760 floats = 42.07 MB
    float* xA = (float*)d_ws;
    float* xB = xA + bufElems;

    {
        dim3 grid((L0 + 255) / 256, B_);
        k_first<<<grid, 256, 0, stream>>>(input, w_first, xA);
    }

    int l = L0;
    float* cur = xA;
    float* nxt = xB;
    for (int i = 0; i < NB; ++i) {
        int lout  = l - 12;
        int tiles = (lout + TTILE - 1) / TTILE;
        dim3 grid(tiles, B_);
        k_block<<<grid, 256, 0, stream>>>(cur, nxt,
                                          conv_a + i * CH * CH * 3,
                                          conv_b + i * CH * CH * 3,
                                          lin_m + i * CH * MM * MM,
                                          filt_d, filt_r, l);
        float* tswap = cur; cur = nxt; nxt = tswap;
        l = lout;
    }

    {
        dim3 grid((LIN_ + 255) / 256, B_);
        k_final<<<grid, 256, 0, stream>>>(cur, w11, w_out, out);
    }
}

// Round 4
// 1889.888 us; speedup vs baseline: 1.1265x; 1.1265x over previous
//
#include <hip/hip_runtime.h>
#include <math.h>

#define B_ 32
#define INLEN 10
#define LIN_ 16384
#define NPOLY 12
#define MM 6
#define CH 20
#define NB 4
#define RECEPT 25
#define L0 16434      // length after first conv
#define TT 60         // outputs per wave-tile (one 64-thread workgroup)
#define XSL 72        // TT + 12 halo
#define XSP 73        // odd padded stride -> conflict-free strided column reads
#define NWW 11        // Legendre windows per tile: wl in [0,10]

__device__ __forceinline__ float gelu_exact(float x) {
    return 0.5f * x * (1.0f + erff(x * 0.70710678118654752440f));
}

// ---------------- first conv: (B,10,16384) wrap-padded -> (B,20,16434) ----------------
__global__ void k_first(const float* __restrict__ in, const float* __restrict__ wf,
                        float* __restrict__ out) {
    int t = blockIdx.x * blockDim.x + threadIdx.x;
    int b = blockIdx.y;
    if (t >= L0) return;
    const float* inb = in + (size_t)b * INLEN * LIN_;
    float xw[INLEN][3];
#pragma unroll
    for (int ci = 0; ci < INLEN; ++ci) {
#pragma unroll
        for (int k = 0; k < 3; ++k) {
            int idx = t + k - RECEPT;
            idx = (idx < 0) ? idx + LIN_ : (idx >= LIN_ ? idx - LIN_ : idx);
            xw[ci][k] = inb[ci * LIN_ + idx];
        }
    }
    float* outb = out + (size_t)b * CH * L0;
#pragma unroll
    for (int co = 0; co < CH; ++co) {
        float acc = 0.f;
#pragma unroll
        for (int ci = 0; ci < INLEN; ++ci)
#pragma unroll
            for (int k = 0; k < 3; ++k)
                acc = fmaf(xw[ci][k], wf[(co * INLEN + ci) * 3 + k], acc);
        outb[(size_t)co * L0 + t] = acc;
    }
}

// ---------------- fused block layer: one fully-independent wave per 60-output tile ----------------
// 64-thread workgroups; no cross-wave communication; __syncthreads() is a trivial
// single-wave fence (lgkmcnt drain), so waves never convoy at barriers.
__global__ __launch_bounds__(64, 4)
void k_block(const float* __restrict__ x, float* __restrict__ xn,
             const float* __restrict__ wA, const float* __restrict__ wB,
             const float* __restrict__ linm, const float* __restrict__ fd,
             const float* __restrict__ fr, int l) {
    const int lout = l - 12;
    const int lane = threadIdx.x;
    const int t0   = blockIdx.x * TT;
    const int b    = blockIdx.y;

    __shared__ float xs[CH][XSP];                                 // 5840 B
    __shared__ __attribute__((aligned(16))) float lxs[NWW * 120]; // 5280 B : [wl][u], u=m*20+c
    __shared__ float fr_s[MM * NPOLY];                            // 288 B
    // total 11408 B -> 14 workgroups (14 waves) per CU

    const float* xb = x + (size_t)b * CH * l;

    if (lane < 36) { fr_s[lane] = fr[lane]; fr_s[36 + lane] = fr[36 + lane]; }

    // stage A: load x tile (zero-fill past end; those outputs are masked)
    for (int i = lane; i < CH * XSL; i += 64) {
        int c = i / XSL, p = i - c * XSL;
        int gp = t0 + p;
        xs[c][p] = (gp < l) ? xb[(size_t)c * l + gp] : 0.f;
    }
    __syncthreads();

    // stage C1: Legendre decomposition per (window, channel); fd reads wave-uniform -> s_load
    for (int item = lane; item < NWW * CH; item += 64) {   // 220 items
        int wl = item / CH, c = item - wl * CH;
        float xv[NPOLY];
#pragma unroll
        for (int k = 0; k < NPOLY; ++k) xv[k] = xs[c][6 * wl + k];
#pragma unroll
        for (int m = 0; m < MM; ++m) {
            float a = 0.f;
#pragma unroll
            for (int k = 0; k < NPOLY; ++k)
                a = fmaf(xv[k], fd[m * NPOLY + k], a);
            lxs[wl * 120 + m * CH + c] = a * 0.5f;
        }
    }
    __syncthreads();

    // stage C2: grouped 6x6 mode mixing in place (u = m*20+c flattened; groups of 6
    // consecutive u -> block-diagonal, each item owns its 6 addresses exclusively)
    for (int item = lane; item < NWW * CH; item += 64) {
        int wl = item / CH, gg = item - wl * CH;
        float iv[MM], ov[MM];
#pragma unroll
        for (int i = 0; i < MM; ++i) iv[i] = lxs[wl * 120 + gg * MM + i];
        const float* lw = linm + gg * (MM * MM);
#pragma unroll
        for (int o = 0; o < MM; ++o) {
            float a = 0.f;
#pragma unroll
            for (int i = 0; i < MM; ++i)
                a = fmaf(iv[i], lw[o * MM + i], a);
            ov[o] = a;
        }
#pragma unroll
        for (int o = 0; o < MM; ++o) lxs[wl * 120 + gg * MM + o] = ov[o];
    }
    __syncthreads();

    // stage B: g = gelu(conv_a(x)) at p = lane (lanes 60..63 are conv_b halo)
    const int p = lane;
    float g[CH];
    {
        float acc[CH];
#pragma unroll
        for (int co = 0; co < CH; ++co) acc[co] = 0.f;
#pragma unroll
        for (int ci = 0; ci < CH; ++ci) {
            float x0 = xs[ci][p + 4];
            float x1 = xs[ci][p + 5];
            float x2 = xs[ci][p + 6];
#pragma unroll
            for (int co = 0; co < CH; ++co) {
                const float* w = wA + (co * CH + ci) * 3;
                acc[co] = fmaf(x0, w[0], acc[co]);
                acc[co] = fmaf(x1, w[1], acc[co]);
                acc[co] = fmaf(x2, w[2], acc[co]);
            }
        }
#pragma unroll
        for (int co = 0; co < CH; ++co) g[co] = gelu_exact(acc[co]);
    }

    // stage D: conv_b via wave shuffles of g (all lanes execute: uniform shuffles)
    float acc[CH];
#pragma unroll
    for (int co = 0; co < CH; ++co) acc[co] = 0.f;
#pragma unroll
    for (int ci = 0; ci < CH; ++ci) {
        float g0 = g[ci];
        float g1 = __shfl_down(g[ci], 1);
        float g2 = __shfl_down(g[ci], 2);
#pragma unroll
        for (int co = 0; co < CH; ++co) {
            const float* w = wB + (co * CH + ci) * 3;
            acc[co] = fmaf(g0, w[0], acc[co]);
            acc[co] = fmaf(g1, w[1], acc[co]);
            acc[co] = fmaf(g2, w[2], acc[co]);
        }
    }

    if (lane < TT && t0 + p < lout) {
        const int r1  = p % 6;
        const int wl1 = p / 6 + 1;
        // reconstruction: m-major, 20 contiguous channels per (window, m) row -> float4 reads
#pragma unroll
        for (int m = 0; m < MM; ++m) {
            float fa = fr_s[m * NPOLY + r1];
            float fb = fr_s[m * NPOLY + r1 + 6];
            const float4* rowA = (const float4*)&lxs[wl1 * 120 + m * CH];
            const float4* rowB = (const float4*)&lxs[(wl1 - 1) * 120 + m * CH];
#pragma unroll
            for (int q = 0; q < 5; ++q) {
                float4 va = rowA[q];
                float4 vb = rowB[q];
                acc[4 * q + 0] = fmaf(va.x, fa, acc[4 * q + 0]);
                acc[4 * q + 1] = fmaf(va.y, fa, acc[4 * q + 1]);
                acc[4 * q + 2] = fmaf(va.z, fa, acc[4 * q + 2]);
                acc[4 * q + 3] = fmaf(va.w, fa, acc[4 * q + 3]);
                acc[4 * q + 0] = fmaf(vb.x, fb, acc[4 * q + 0]);
                acc[4 * q + 1] = fmaf(vb.y, fb, acc[4 * q + 1]);
                acc[4 * q + 2] = fmaf(vb.z, fb, acc[4 * q + 2]);
                acc[4 * q + 3] = fmaf(vb.w, fb, acc[4 * q + 3]);
            }
        }
        float* xnb = xn + (size_t)b * CH * lout;
#pragma unroll
        for (int co = 0; co < CH; ++co)
            xnb[(size_t)co * lout + t0 + p] = gelu_exact(acc[co]);
    }
}

// ---------------- final: gelu(20->128) -> 128->1, slice to 16384 ----------------
__global__ void k_final(const float* __restrict__ x, const float* __restrict__ w11,
                        const float* __restrict__ wout, float* __restrict__ out) {
    int t = blockIdx.x * blockDim.x + threadIdx.x;
    int b = blockIdx.y;
    if (t >= LIN_) return;
    const int l4 = L0 - NB * 12;   // 16386
    const float* xb = x + (size_t)b * CH * l4;
    float xv[CH];
#pragma unroll
    for (int c = 0; c < CH; ++c) xv[c] = xb[(size_t)c * l4 + t];
    float acc = 0.f;
    for (int h = 0; h < 128; ++h) {
        float hv = 0.f;
#pragma unroll
        for (int c = 0; c < CH; ++c)
            hv = fmaf(xv[c], w11[h * CH + c], hv);
        acc = fmaf(gelu_exact(hv), wout[h], acc);
    }
    out[(size_t)b * LIN_ + t] = acc;
}

extern "C" void kernel_launch(void* const* d_in, const int* in_sizes, int n_in,
                              void* d_out, int out_size, void* d_ws, size_t ws_size,
                              hipStream_t stream) {
    const float* input   = (const float*)d_in[0];
    const float* w_first = (const float*)d_in[1];
    const float* conv_a  = (const float*)d_in[2];
    const float* conv_b  = (const float*)d_in[3];
    const float* lin_m   = (const float*)d_in[4];
    const float* w11     = (const float*)d_in[5];
    const float* w_out   = (const float*)d_in[6];
    const float* filt_d  = (const float*)d_in[7];
    const float* filt_r  = (const float*)d_in[8];
    float* out = (float*)d_out;

    const size_t bufElems = (size_t)B_ * CH * L0;   // 10,517,760 floats = 42.07 MB
    float* xA = (float*)d_ws;
    float* xB = xA + bufElems;

    {
        dim3 grid((L0 + 255) / 256, B_);
        k_first<<<grid, 256, 0, stream>>>(input, w_first, xA);
    }

    int l = L0;
    float* cur = xA;
    float* nxt = xB;
    for (int i = 0; i < NB; ++i) {
        int lout  = l - 12;
        int tiles = (lout + TT - 1) / TT;
        dim3 grid(tiles, B_);
        k_block<<<grid, 64, 0, stream>>>(cur, nxt,
                                         conv_a + i * CH * CH * 3,
                                         conv_b + i * CH * CH * 3,
                                         lin_m + i * CH * MM * MM,
                                         filt_d, filt_r, l);
        float* tswap = cur; cur = nxt; nxt = tswap;
        l = lout;
    }

    {
        dim3 grid((LIN_ + 255) / 256, B_);
        k_final<<<grid, 256, 0, stream>>>(cur, w11, w_out, out);
    }
}

// Round 5
// 1454.787 us; speedup vs baseline: 1.4635x; 1.2991x over previous
//
#include <hip/hip_runtime.h>
#include <math.h>

#define B_ 32
#define INLEN 10
#define LIN_ 16384
#define NPOLY 12
#define MM 6
#define CH 20
#define NB 4
#define RECEPT 25
#define L0 16434      // length after first conv
#define TT 60         // outputs per wave-tile (one 64-thread workgroup)
#define XSL 72        // TT + 12 halo
#define XSP 73        // odd padded stride -> conflict-free strided column reads
#define NWW 11        // Legendre windows per tile: wl in [0,10]

__device__ __forceinline__ float gelu_exact(float x) {
    return 0.5f * x * (1.0f + erff(x * 0.70710678118654752440f));
}

// ---------------- first conv: (B,10,16384) wrap-padded -> (B,20,16434) ----------------
__global__ void k_first(const float* __restrict__ in, const float* __restrict__ wf,
                        float* __restrict__ out) {
    int t = blockIdx.x * blockDim.x + threadIdx.x;
    int b = blockIdx.y;
    if (t >= L0) return;
    const float* inb = in + (size_t)b * INLEN * LIN_;
    float xw[INLEN][3];
#pragma unroll
    for (int ci = 0; ci < INLEN; ++ci) {
#pragma unroll
        for (int k = 0; k < 3; ++k) {
            int idx = t + k - RECEPT;
            idx = (idx < 0) ? idx + LIN_ : (idx >= LIN_ ? idx - LIN_ : idx);
            xw[ci][k] = inb[ci * LIN_ + idx];
        }
    }
    float* outb = out + (size_t)b * CH * L0;
#pragma unroll
    for (int co = 0; co < CH; ++co) {
        float acc = 0.f;
#pragma unroll
        for (int ci = 0; ci < INLEN; ++ci)
#pragma unroll
            for (int k = 0; k < 3; ++k)
                acc = fmaf(xw[ci][k], wf[(co * INLEN + ci) * 3 + k], acc);
        outb[(size_t)co * L0 + t] = acc;
    }
}

// ---------------- fused block layer: one fully-independent wave per 60-output tile ----------------
// 64-thread workgroups; no cross-wave communication. amdgpu_waves_per_eu(3,8) sets the
// register budget to ~170 VGPRs (natural pressure ~88) -- prevents the 64-VGPR spill
// catastrophe seen with __launch_bounds__ occupancy floors in R2/R3/R4.
__global__ void __launch_bounds__(64)
__attribute__((amdgpu_waves_per_eu(3, 8)))
k_block(const float* __restrict__ x, float* __restrict__ xn,
        const float* __restrict__ wA, const float* __restrict__ wB,
        const float* __restrict__ linm, const float* __restrict__ fd,
        const float* __restrict__ fr, int l) {
    const int lout = l - 12;
    const int lane = threadIdx.x;
    const int t0   = blockIdx.x * TT;
    const int b    = blockIdx.y;

    __shared__ float xs[CH][XSP];                                 // 5840 B
    __shared__ __attribute__((aligned(16))) float lxs[NWW * 120]; // 5280 B : [wl][u], u=m*20+c
    __shared__ float fr_s[MM * NPOLY];                            // 288 B
    // total 11408 B -> ~13 single-wave workgroups per CU

    const float* xb = x + (size_t)b * CH * l;

    if (lane < 36) { fr_s[lane] = fr[lane]; fr_s[36 + lane] = fr[36 + lane]; }

    // stage A: load x tile (zero-fill past end; those outputs are masked)
    for (int i = lane; i < CH * XSL; i += 64) {
        int c = i / XSL, p = i - c * XSL;
        int gp = t0 + p;
        xs[c][p] = (gp < l) ? xb[(size_t)c * l + gp] : 0.f;
    }
    __syncthreads();

    // stage C1: Legendre decomposition per (window, channel); fd reads wave-uniform -> s_load
    for (int item = lane; item < NWW * CH; item += 64) {   // 220 items
        int wl = item / CH, c = item - wl * CH;
        float xv[NPOLY];
#pragma unroll
        for (int k = 0; k < NPOLY; ++k) xv[k] = xs[c][6 * wl + k];
#pragma unroll
        for (int m = 0; m < MM; ++m) {
            float a = 0.f;
#pragma unroll
            for (int k = 0; k < NPOLY; ++k)
                a = fmaf(xv[k], fd[m * NPOLY + k], a);
            lxs[wl * 120 + m * CH + c] = a * 0.5f;
        }
    }
    __syncthreads();

    // stage C2: grouped 6x6 mode mixing in place (u = m*20+c flattened; groups of 6
    // consecutive u -> block-diagonal, each item owns its 6 addresses exclusively)
    for (int item = lane; item < NWW * CH; item += 64) {
        int wl = item / CH, gg = item - wl * CH;
        float iv[MM], ov[MM];
#pragma unroll
        for (int i = 0; i < MM; ++i) iv[i] = lxs[wl * 120 + gg * MM + i];
        const float* lw = linm + gg * (MM * MM);
#pragma unroll
        for (int o = 0; o < MM; ++o) {
            float a = 0.f;
#pragma unroll
            for (int i = 0; i < MM; ++i)
                a = fmaf(iv[i], lw[o * MM + i], a);
            ov[o] = a;
        }
#pragma unroll
        for (int o = 0; o < MM; ++o) lxs[wl * 120 + gg * MM + o] = ov[o];
    }
    __syncthreads();

    // stage B: g = gelu(conv_a(x)) at p = lane (lanes 60..63 are conv_b halo)
    const int p = lane;
    float g[CH];
    {
        float acc[CH];
#pragma unroll
        for (int co = 0; co < CH; ++co) acc[co] = 0.f;
#pragma unroll
        for (int ci = 0; ci < CH; ++ci) {
            float x0 = xs[ci][p + 4];
            float x1 = xs[ci][p + 5];
            float x2 = xs[ci][p + 6];
#pragma unroll
            for (int co = 0; co < CH; ++co) {
                const float* w = wA + (co * CH + ci) * 3;
                acc[co] = fmaf(x0, w[0], acc[co]);
                acc[co] = fmaf(x1, w[1], acc[co]);
                acc[co] = fmaf(x2, w[2], acc[co]);
            }
        }
#pragma unroll
        for (int co = 0; co < CH; ++co) g[co] = gelu_exact(acc[co]);
    }

    // stage D: conv_b via wave shuffles of g (all lanes execute: uniform shuffles)
    float acc[CH];
#pragma unroll
    for (int co = 0; co < CH; ++co) acc[co] = 0.f;
#pragma unroll
    for (int ci = 0; ci < CH; ++ci) {
        float g0 = g[ci];
        float g1 = __shfl_down(g[ci], 1);
        float g2 = __shfl_down(g[ci], 2);
#pragma unroll
        for (int co = 0; co < CH; ++co) {
            const float* w = wB + (co * CH + ci) * 3;
            acc[co] = fmaf(g0, w[0], acc[co]);
            acc[co] = fmaf(g1, w[1], acc[co]);
            acc[co] = fmaf(g2, w[2], acc[co]);
        }
    }

    if (lane < TT && t0 + p < lout) {
        const int r1  = p % 6;
        const int wl1 = p / 6 + 1;
        // reconstruction: m-major, 20 contiguous channels per (window, m) row -> float4 reads
#pragma unroll
        for (int m = 0; m < MM; ++m) {
            float fa = fr_s[m * NPOLY + r1];
            float fb = fr_s[m * NPOLY + r1 + 6];
            const float4* rowA = (const float4*)&lxs[wl1 * 120 + m * CH];
            const float4* rowB = (const float4*)&lxs[(wl1 - 1) * 120 + m * CH];
#pragma unroll
            for (int q = 0; q < 5; ++q) {
                float4 va = rowA[q];
                float4 vb = rowB[q];
                acc[4 * q + 0] = fmaf(va.x, fa, acc[4 * q + 0]);
                acc[4 * q + 1] = fmaf(va.y, fa, acc[4 * q + 1]);
                acc[4 * q + 2] = fmaf(va.z, fa, acc[4 * q + 2]);
                acc[4 * q + 3] = fmaf(va.w, fa, acc[4 * q + 3]);
                acc[4 * q + 0] = fmaf(vb.x, fb, acc[4 * q + 0]);
                acc[4 * q + 1] = fmaf(vb.y, fb, acc[4 * q + 1]);
                acc[4 * q + 2] = fmaf(vb.z, fb, acc[4 * q + 2]);
                acc[4 * q + 3] = fmaf(vb.w, fb, acc[4 * q + 3]);
            }
        }
        float* xnb = xn + (size_t)b * CH * lout;
#pragma unroll
        for (int co = 0; co < CH; ++co)
            xnb[(size_t)co * lout + t0 + p] = gelu_exact(acc[co]);
    }
}

// ---------------- final: gelu(20->128) -> 128->1, slice to 16384 ----------------
__global__ void k_final(const float* __restrict__ x, const float* __restrict__ w11,
                        const float* __restrict__ wout, float* __restrict__ out) {
    int t = blockIdx.x * blockDim.x + threadIdx.x;
    int b = blockIdx.y;
    if (t >= LIN_) return;
    const int l4 = L0 - NB * 12;   // 16386
    const float* xb = x + (size_t)b * CH * l4;
    float xv[CH];
#pragma unroll
    for (int c = 0; c < CH; ++c) xv[c] = xb[(size_t)c * l4 + t];
    float acc = 0.f;
    for (int h = 0; h < 128; ++h) {
        float hv = 0.f;
#pragma unroll
        for (int c = 0; c < CH; ++c)
            hv = fmaf(xv[c], w11[h * CH + c], hv);
        acc = fmaf(gelu_exact(hv), wout[h], acc);
    }
    out[(size_t)b * LIN_ + t] = acc;
}

extern "C" void kernel_launch(void* const* d_in, const int* in_sizes, int n_in,
                              void* d_out, int out_size, void* d_ws, size_t ws_size,
                              hipStream_t stream) {
    const float* input   = (const float*)d_in[0];
    const float* w_first = (const float*)d_in[1];
    const float* conv_a  = (const float*)d_in[2];
    const float* conv_b  = (const float*)d_in[3];
    const float* lin_m   = (const float*)d_in[4];
    const float* w11     = (const float*)d_in[5];
    const float* w_out   = (const float*)d_in[6];
    const float* filt_d  = (const float*)d_in[7];
    const float* filt_r  = (const float*)d_in[8];
    float* out = (float*)d_out;

    const size_t bufElems = (size_t)B_ * CH * L0;   // 10,517,760 floats = 42.07 MB
    float* xA = (float*)d_ws;
    float* xB = xA + bufElems;

    {
        dim3 grid((L0 + 255) / 256, B_);
        k_first<<<grid, 256, 0, stream>>>(input, w_first, xA);
    }

    int l = L0;
    float* cur = xA;
    float* nxt = xB;
    for (int i = 0; i < NB; ++i) {
        int lout  = l - 12;
        int tiles = (lout + TT - 1) / TT;
        dim3 grid(tiles, B_);
        k_block<<<grid, 64, 0, stream>>>(cur, nxt,
                                         conv_a + i * CH * CH * 3,
                                         conv_b + i * CH * CH * 3,
                                         lin_m + i * CH * MM * MM,
                                         filt_d, filt_r, l);
        float* tswap = cur; cur = nxt; nxt = tswap;
        l = lout;
    }

    {
        dim3 grid((LIN_ + 255) / 256, B_);
        k_final<<<grid, 256, 0, stream>>>(cur, w11, w_out, out);
    }
}

// Round 6
// 1113.016 us; speedup vs baseline: 1.9128x; 1.3071x over previous
//
#include <hip/hip_runtime.h>
#include <math.h>

#define B_ 32
#define INLEN 10
#define LIN_ 16384
#define NPOLY 12
#define MM 6
#define CH 20
#define NB 4
#define RECEPT 25
#define L0 16434      // length after first conv
#define TTILE 240     // outputs per tile (multiple of 6; 4 waves x 60)
#define NW 41         // windows covering the tile: wl in [0,40]
#define XSL 252       // TTILE + 12 halo (all stages stay below 252)
#define XSP 253       // 253 mod 32 = 29 -> strided column reads conflict-free

__device__ __forceinline__ float gelu_exact(float x) {
    return 0.5f * x * (1.0f + erff(x * 0.70710678118654752440f));
}

// ---------------- first conv: (B,10,16384) wrap-padded -> (B,20,16434) ----------------
__global__ void k_first(const float* __restrict__ in, const float* __restrict__ wf,
                        float* __restrict__ out) {
    int t = blockIdx.x * blockDim.x + threadIdx.x;
    int b = blockIdx.y;
    if (t >= L0) return;
    const float* inb = in + (size_t)b * INLEN * LIN_;
    float xw[INLEN][3];
#pragma unroll
    for (int ci = 0; ci < INLEN; ++ci) {
#pragma unroll
        for (int k = 0; k < 3; ++k) {
            int idx = t + k - RECEPT;
            idx = (idx < 0) ? idx + LIN_ : (idx >= LIN_ ? idx - LIN_ : idx);
            xw[ci][k] = inb[ci * LIN_ + idx];
        }
    }
    float* outb = out + (size_t)b * CH * L0;
#pragma unroll
    for (int co = 0; co < CH; ++co) {
        float acc = 0.f;
#pragma unroll
        for (int ci = 0; ci < INLEN; ++ci)
#pragma unroll
            for (int k = 0; k < 3; ++k)
                acc = fmaf(xw[ci][k], wf[(co * INLEN + ci) * 3 + k], acc);
        outb[(size_t)co * L0 + t] = acc;
    }
}

// ---------------- fused block: residual conv path + Legendre multiwavelet path ----------------
// R1-proven traffic-clean shape: 256 threads = 4 waves; wave w owns 60 outputs at
// p = w*60 + lane (lanes 60..63 are conv_b shuffle halo). (256,2) -> 88 VGPR, no spill.
__global__ __launch_bounds__(256, 2)
void k_block(const float* __restrict__ x, float* __restrict__ xn,
             const float* __restrict__ wA, const float* __restrict__ wB,
             const float* __restrict__ linm, const float* __restrict__ fd,
             const float* __restrict__ fr, int l) {
    const int lout = l - 12;
    const int tid  = threadIdx.x;
    const int lane = tid & 63;
    const int wv   = tid >> 6;
    const int p    = wv * 60 + lane;           // local position this thread owns
    const int t0   = blockIdx.x * TTILE;       // multiple of 6
    const int b    = blockIdx.y;

    __shared__ float xs[CH][XSP];                                // 20240 B
    __shared__ __attribute__((aligned(16))) float lxs[NW * 120]; // 19680 B : [wl][u], u=m*20+c
    __shared__ float fr_s[MM * NPOLY];                           // 288 B
    // total ~40.2 KB

    const float* xb = x + (size_t)b * CH * l;

    if (tid < MM * NPOLY) fr_s[tid] = fr[tid];

    // stage A: load x tile (zero-fill past end; those outputs are masked)
#pragma unroll
    for (int c = 0; c < CH; ++c) {
        if (tid < XSL) {
            int gp = t0 + tid;
            xs[c][tid] = (gp < l) ? xb[(size_t)c * l + gp] : 0.f;
        }
    }
    __syncthreads();

    // stage C1: Legendre decomposition per (window, channel); fd reads wave-uniform -> s_load
    for (int item = tid; item < NW * CH; item += 256) {   // 820 items
        int wl = item / CH, c = item - wl * CH;
        float xv[NPOLY];
#pragma unroll
        for (int k = 0; k < NPOLY; ++k) xv[k] = xs[c][6 * wl + k];
#pragma unroll
        for (int m = 0; m < MM; ++m) {
            float a = 0.f;
#pragma unroll
            for (int k = 0; k < NPOLY; ++k)
                a = fmaf(xv[k], fd[m * NPOLY + k], a);
            lxs[wl * 120 + m * CH + c] = a * 0.5f;
        }
    }
    __syncthreads();

    // stage C2: grouped 6x6 mode mixing in place (u = m*20+c flattened; groups of 6
    // consecutive u -> block-diagonal, each item owns its 6 addresses exclusively)
    for (int item = tid; item < NW * CH; item += 256) {
        int wl = item / CH, gg = item - wl * CH;
        float iv[MM], ov[MM];
#pragma unroll
        for (int i = 0; i < MM; ++i) iv[i] = lxs[wl * 120 + gg * MM + i];
        const float* lw = linm + gg * (MM * MM);
#pragma unroll
        for (int o = 0; o < MM; ++o) {
            float a = 0.f;
#pragma unroll
            for (int i = 0; i < MM; ++i)
                a = fmaf(iv[i], lw[o * MM + i], a);
            ov[o] = a;
        }
#pragma unroll
        for (int o = 0; o < MM; ++o) lxs[wl * 120 + gg * MM + o] = ov[o];
    }
    __syncthreads();

    // stage B: g = gelu(conv_a(x)) at this thread's position (registers; after barriers
    // so g does not live across any fence -> lower pressure than R1)
    float g[CH];
    {
        float acc[CH];
#pragma unroll
        for (int co = 0; co < CH; ++co) acc[co] = 0.f;
#pragma unroll
        for (int ci = 0; ci < CH; ++ci) {
            float x0 = xs[ci][p + 4];
            float x1 = xs[ci][p + 5];
            float x2 = xs[ci][p + 6];
#pragma unroll
            for (int co = 0; co < CH; ++co) {
                const float* w = wA + (co * CH + ci) * 3;
                acc[co] = fmaf(x0, w[0], acc[co]);
                acc[co] = fmaf(x1, w[1], acc[co]);
                acc[co] = fmaf(x2, w[2], acc[co]);
            }
        }
#pragma unroll
        for (int co = 0; co < CH; ++co) g[co] = gelu_exact(acc[co]);
    }

    // stage D: conv_b via wave shuffles of g (all lanes execute: uniform shuffles)
    float acc[CH];
#pragma unroll
    for (int co = 0; co < CH; ++co) acc[co] = 0.f;
#pragma unroll
    for (int ci = 0; ci < CH; ++ci) {
        float g0 = g[ci];
        float g1 = __shfl_down(g[ci], 1);
        float g2 = __shfl_down(g[ci], 2);
#pragma unroll
        for (int co = 0; co < CH; ++co) {
            const float* w = wB + (co * CH + ci) * 3;
            acc[co] = fmaf(g0, w[0], acc[co]);
            acc[co] = fmaf(g1, w[1], acc[co]);
            acc[co] = fmaf(g2, w[2], acc[co]);
        }
    }

    if (lane < 60 && t0 + p < lout) {
        const int r1  = p % 6;
        const int wl1 = p / 6 + 1;
        // reconstruction: m-major, 20 contiguous channels per (window, m) row -> float4 reads
#pragma unroll
        for (int m = 0; m < MM; ++m) {
            float fa = fr_s[m * NPOLY + r1];
            float fb = fr_s[m * NPOLY + r1 + 6];
            const float4* rowA = (const float4*)&lxs[wl1 * 120 + m * CH];
            const float4* rowB = (const float4*)&lxs[(wl1 - 1) * 120 + m * CH];
#pragma unroll
            for (int q = 0; q < 5; ++q) {
                float4 va = rowA[q];
                float4 vb = rowB[q];
                acc[4 * q + 0] = fmaf(va.x, fa, acc[4 * q + 0]);
                acc[4 * q + 1] = fmaf(va.y, fa, acc[4 * q + 1]);
                acc[4 * q + 2] = fmaf(va.z, fa, acc[4 * q + 2]);
                acc[4 * q + 3] = fmaf(va.w, fa, acc[4 * q + 3]);
                acc[4 * q + 0] = fmaf(vb.x, fb, acc[4 * q + 0]);
                acc[4 * q + 1] = fmaf(vb.y, fb, acc[4 * q + 1]);
                acc[4 * q + 2] = fmaf(vb.z, fb, acc[4 * q + 2]);
                acc[4 * q + 3] = fmaf(vb.w, fb, acc[4 * q + 3]);
            }
        }
        float* xnb = xn + (size_t)b * CH * lout;
#pragma unroll
        for (int co = 0; co < CH; ++co)
            xnb[(size_t)co * lout + t0 + p] = gelu_exact(acc[co]);
    }
}

// ---------------- final: gelu(20->128) -> 128->1, slice to 16384 ----------------
__global__ void k_final(const float* __restrict__ x, const float* __restrict__ w11,
                        const float* __restrict__ wout, float* __restrict__ out) {
    int t = blockIdx.x * blockDim.x + threadIdx.x;
    int b = blockIdx.y;
    if (t >= LIN_) return;
    const int l4 = L0 - NB * 12;   // 16386
    const float* xb = x + (size_t)b * CH * l4;
    float xv[CH];
#pragma unroll
    for (int c = 0; c < CH; ++c) xv[c] = xb[(size_t)c * l4 + t];
    float acc = 0.f;
    for (int h = 0; h < 128; ++h) {
        float hv = 0.f;
#pragma unroll
        for (int c = 0; c < CH; ++c)
            hv = fmaf(xv[c], w11[h * CH + c], hv);
        acc = fmaf(gelu_exact(hv), wout[h], acc);
    }
    out[(size_t)b * LIN_ + t] = acc;
}

extern "C" void kernel_launch(void* const* d_in, const int* in_sizes, int n_in,
                              void* d_out, int out_size, void* d_ws, size_t ws_size,
                              hipStream_t stream) {
    const float* input   = (const float*)d_in[0];
    const float* w_first = (const float*)d_in[1];
    const float* conv_a  = (const float*)d_in[2];
    const float* conv_b  = (const float*)d_in[3];
    const float* lin_m   = (const float*)d_in[4];
    const float* w11     = (const float*)d_in[5];
    const float* w_out   = (const float*)d_in[6];
    const float* filt_d  = (const float*)d_in[7];
    const float* filt_r  = (const float*)d_in[8];
    float* out = (float*)d_out;

    const size_t bufElems = (size_t)B_ * CH * L0;   // 10,517,760 floats = 42.07 MB
    float* xA = (float*)d_ws;
    float* xB = xA + bufElems;

    {
        dim3 grid((L0 + 255) / 256, B_);
        k_first<<<grid, 256, 0, stream>>>(input, w_first, xA);
    }

    int l = L0;
    float* cur = xA;
    float* nxt = xB;
    for (int i = 0; i < NB; ++i) {
        int lout  = l - 12;
        int tiles = (lout + TTILE - 1) / TTILE;
        dim3 grid(tiles, B_);
        k_block<<<grid, 256, 0, stream>>>(cur, nxt,
                                          conv_a + i * CH * CH * 3,
                                          conv_b + i * CH * CH * 3,
                                          lin_m + i * CH * MM * MM,
                                          filt_d, filt_r, l);
        float* tswap = cur; cur = nxt; nxt = tswap;
        l = lout;
    }

    {
        dim3 grid((LIN_ + 255) / 256, B_);
        k_final<<<grid, 256, 0, stream>>>(cur, w11, w_out, out);
    }
}